// Round 2
// baseline (1031.597 us; speedup 1.0000x reference)
//
#include <hip/hip_runtime.h>
#include <hip/hip_bf16.h>
#include <math.h>

// Problem constants
#define B_ 2
#define L_ 1024
#define D_ 1024
#define H_ 16
#define DH 64

// ---------------------------------------------------------------------------
// Generic fp32 SMEM-tiled GEMM body: C[M,N] = A[M,K] @ B[K,N], row-major.
// 256 threads. (BM/TM)*(BN/TN) must == 256.
// ---------------------------------------------------------------------------
template<int BM, int BN, int BK, int TM, int TN>
__device__ __forceinline__ void gemm_tile(const float* __restrict__ A,
                                          const float* __restrict__ B,
                                          float* __restrict__ C,
                                          int M, int N, int K,
                                          int bx, int by) {
  __shared__ float As[BK][BM + 1];   // transposed staging: As[k][m]
  __shared__ float Bs[BK][BN + 1];

  const int tid = threadIdx.x;
  const int tx = tid % (BN / TN);
  const int ty = tid / (BN / TN);
  const int row0 = by * BM;
  const int col0 = bx * BN;

  float acc[TM][TN] = {};

  for (int k0 = 0; k0 < K; k0 += BK) {
    // Stage A tile (BM x BK) via float4, transpose into As
    constexpr int AV = BM * BK / 4;
    #pragma unroll
    for (int idx = tid; idx < AV; idx += 256) {
      int m  = idx / (BK / 4);
      int k4 = (idx % (BK / 4)) * 4;
      float4 av = *(const float4*)&A[(size_t)(row0 + m) * K + k0 + k4];
      As[k4 + 0][m] = av.x; As[k4 + 1][m] = av.y;
      As[k4 + 2][m] = av.z; As[k4 + 3][m] = av.w;
    }
    // Stage B tile (BK x BN) via float4
    constexpr int BV = BK * BN / 4;
    #pragma unroll
    for (int idx = tid; idx < BV; idx += 256) {
      int kk = idx / (BN / 4);
      int n4 = (idx % (BN / 4)) * 4;
      float4 bv = *(const float4*)&B[(size_t)(k0 + kk) * N + col0 + n4];
      Bs[kk][n4 + 0] = bv.x; Bs[kk][n4 + 1] = bv.y;
      Bs[kk][n4 + 2] = bv.z; Bs[kk][n4 + 3] = bv.w;
    }
    __syncthreads();

    #pragma unroll
    for (int kk = 0; kk < BK; ++kk) {
      float a[TM], b[TN];
      #pragma unroll
      for (int m = 0; m < TM; ++m) a[m] = As[kk][ty * TM + m];
      #pragma unroll
      for (int n = 0; n < TN; ++n) b[n] = Bs[kk][tx * TN + n];
      #pragma unroll
      for (int m = 0; m < TM; ++m)
        #pragma unroll
        for (int n = 0; n < TN; ++n)
          acc[m][n] += a[m] * b[n];
    }
    __syncthreads();
  }

  #pragma unroll
  for (int m = 0; m < TM; ++m) {
    #pragma unroll
    for (int n = 0; n < TN; n += 4) {
      float4 o = { acc[m][n], acc[m][n+1], acc[m][n+2], acc[m][n+3] };
      *(float4*)&C[(size_t)(row0 + ty * TM + m) * N + col0 + tx * TN + n] = o;
    }
  }
}

// z-batched projection GEMMs: z=0: q=E@Wq ; z=1: k=Ev@Wke ; z=2: v=Ev@Wv ;
// z=3: Qp=R@Wkr (M=1024, extra y-blocks bail out).
__global__ __launch_bounds__(256) void proj_gemm(
    const float* __restrict__ E,  const float* __restrict__ Ev,
    const float* __restrict__ R,
    const float* __restrict__ Wq, const float* __restrict__ Wke,
    const float* __restrict__ Wkr, const float* __restrict__ Wv,
    float* __restrict__ q, float* __restrict__ k,
    float* __restrict__ v, float* __restrict__ Qp) {
  const int z = blockIdx.z;
  const float* A; const float* Bm; float* C; int M;
  if (z == 0)      { A = E;  Bm = Wq;  C = q;  M = B_ * L_; }
  else if (z == 1) { A = Ev; Bm = Wke; C = k;  M = B_ * L_; }
  else if (z == 2) { A = Ev; Bm = Wv;  C = v;  M = B_ * L_; }
  else             { A = R;  Bm = Wkr; C = Qp; M = L_;      }
  if ((int)blockIdx.y * 128 >= M) return;
  gemm_tile<128, 128, 8, 8, 8>(A, Bm, C, M, D_, D_, blockIdx.x, blockIdx.y);
}

// Output projection: P = O @ Wo_w  (2048x1024x1024). Smaller tiles -> 512 blocks.
__global__ __launch_bounds__(256) void gemm_out(
    const float* __restrict__ A, const float* __restrict__ Bm,
    float* __restrict__ C) {
  gemm_tile<64, 64, 16, 4, 4>(A, Bm, C, B_ * L_, D_, D_, blockIdx.x, blockIdx.y);
}

// ---------------------------------------------------------------------------
// Attention: one block = 16 query rows of one (b,h). Flash-style over 64-col
// K tiles with online softmax.
//   s_j = (q_i+cb_h).k_j + (j<=i ? (q_i+pb_h).Q[L-1-i+j] : 0);  full softmax.
// Thread layout: r = tid>>4 (row 0..15), c = tid&15 (16 lanes per row).
// Each thread owns output dims [4c,4c+4) and 4 score columns jj = c+16t.
// ---------------------------------------------------------------------------
#define RT 16
#define JT 64

__global__ __launch_bounds__(256) void attn_kernel(
    const float* __restrict__ q, const float* __restrict__ k,
    const float* __restrict__ v, const float* __restrict__ Qp,
    const float* __restrict__ cb, const float* __restrict__ pb,
    float* __restrict__ O) {
  __shared__ float qcs[RT][DH];        // q + cb  (broadcast reads)
  __shared__ float qps[RT][DH];        // q + pb
  __shared__ float kt[JT][DH + 4];     // +4 pad: 2-way banks max on row-strided reads
  __shared__ float Qt[JT + RT][DH + 4];
  __shared__ float P[RT][JT];

  const int tid = threadIdx.x;
  const int nrt = L_ / RT;             // 64
  const int b  = blockIdx.x / (H_ * nrt);
  const int hh = (blockIdx.x / nrt) % H_;
  const int i0 = (blockIdx.x % nrt) * RT;

  const int r = tid >> 4;
  const int c = tid & 15;
  const int i = i0 + r;

  // Stage biased q rows
  for (int idx = tid; idx < RT * DH; idx += 256) {
    int rr = idx / DH, d = idx % DH;
    float qv = q[((size_t)b * L_ + (i0 + rr)) * D_ + hh * DH + d];
    qcs[rr][d] = qv + cb[hh * DH + d];
    qps[rr][d] = qv + pb[hh * DH + d];
  }

  float m_r = -1e30f, l_r = 0.f;
  float4 oacc = {0.f, 0.f, 0.f, 0.f};

  for (int j0 = 0; j0 < L_; j0 += JT) {
    __syncthreads();   // protect kt/Qt (and first-iter qcs/qps staging)

    // Stage K tile: JT x 64 floats
    for (int idx = tid; idx < JT * (DH / 4); idx += 256) {
      int jj = idx / (DH / 4), d4 = (idx % (DH / 4)) * 4;
      *(float4*)&kt[jj][d4] =
          *(const float4*)&k[((size_t)b * L_ + (j0 + jj)) * D_ + hh * DH + d4];
    }
    // Stage positional-Q window: rows m = mbase .. mbase+79 (clamped)
    const int mbase = (L_ - RT - i0) + j0;   // = L-1-(i0+15)+j0, >= 0 always
    for (int idx = tid; idx < (JT + RT) * (DH / 4); idx += 256) {
      int mm = idx / (DH / 4), d4 = (idx % (DH / 4)) * 4;
      int m = mbase + mm;
      float4 qv = {0.f, 0.f, 0.f, 0.f};
      if (m < L_) qv = *(const float4*)&Qp[(size_t)m * D_ + hh * DH + d4];
      *(float4*)&Qt[mm][d4] = qv;
    }
    __syncthreads();

    // Scores: 4 columns per thread
    float s[4];
    #pragma unroll
    for (int t = 0; t < 4; ++t) {
      const int jj = c + 16 * t;
      const int j = j0 + jj;
      float acc = 0.f;
      #pragma unroll
      for (int d4 = 0; d4 < DH; d4 += 4) {
        float4 kv = *(const float4*)&kt[jj][d4];
        float4 qv = *(const float4*)&qcs[r][d4];
        acc += qv.x * kv.x + qv.y * kv.y + qv.z * kv.z + qv.w * kv.w;
      }
      if (j <= i) {
        const int mm = (RT - 1 - r) + jj;    // Qt row for m = L-1-i+j
        float pacc = 0.f;
        #pragma unroll
        for (int d4 = 0; d4 < DH; d4 += 4) {
          float4 Qv = *(const float4*)&Qt[mm][d4];
          float4 qv = *(const float4*)&qps[r][d4];
          pacc += qv.x * Qv.x + qv.y * Qv.y + qv.z * Qv.z + qv.w * Qv.w;
        }
        acc += pacc;
      }
      s[t] = acc;
    }

    // Row-wide online softmax (16 lanes per row)
    float tm = fmaxf(fmaxf(s[0], s[1]), fmaxf(s[2], s[3]));
    #pragma unroll
    for (int off = 1; off < 16; off <<= 1)
      tm = fmaxf(tm, __shfl_xor(tm, off, 64));
    const float mnew = fmaxf(m_r, tm);
    const float scale = __expf(m_r - mnew);

    float ls = 0.f;
    #pragma unroll
    for (int t = 0; t < 4; ++t) {
      float p = __expf(s[t] - mnew);
      ls += p;
      P[r][c + 16 * t] = p;
    }
    #pragma unroll
    for (int off = 1; off < 16; off <<= 1)
      ls += __shfl_xor(ls, off, 64);
    l_r = l_r * scale + ls;
    m_r = mnew;
    oacc.x *= scale; oacc.y *= scale; oacc.z *= scale; oacc.w *= scale;

    __syncthreads();   // P visible (also keeps waves in phase before restage)

    // O += P @ V   (each thread: dims 4c..4c+3, all 64 jj of its row)
    #pragma unroll 4
    for (int jj = 0; jj < JT; ++jj) {
      const float p = P[r][jj];
      const float4 vv =
          *(const float4*)&v[((size_t)b * L_ + (j0 + jj)) * D_ + hh * DH + c * 4];
      oacc.x += p * vv.x; oacc.y += p * vv.y;
      oacc.z += p * vv.z; oacc.w += p * vv.w;
    }
  }

  const float inv = 1.f / l_r;
  float4 res = { oacc.x * inv, oacc.y * inv, oacc.z * inv, oacc.w * inv };
  *(float4*)&O[((size_t)b * L_ + i) * D_ + hh * DH + c * 4] = res;
}

// ---------------------------------------------------------------------------
// res = Ev + proj + Wo_b; LayerNorm(res) * g + b. One block per row.
// ---------------------------------------------------------------------------
__global__ __launch_bounds__(256) void ln_kernel(
    const float* __restrict__ Ev, const float* __restrict__ proj,
    const float* __restrict__ Wo_b, const float* __restrict__ g,
    const float* __restrict__ beta, float* __restrict__ out) {
  const int row = blockIdx.x;
  __shared__ float buf[D_];
  __shared__ float red[8];
  const int tid = threadIdx.x;
  const int d = tid * 4;   // 256 threads x 4 = 1024

  float4 e  = *(const float4*)&Ev[(size_t)row * D_ + d];
  float4 p  = *(const float4*)&proj[(size_t)row * D_ + d];
  float4 wb = *(const float4*)&Wo_b[d];
  float4 rr = { e.x + p.x + wb.x, e.y + p.y + wb.y,
                e.z + p.z + wb.z, e.w + p.w + wb.w };
  *(float4*)&buf[d] = rr;
  float sum = rr.x + rr.y + rr.z + rr.w;
  float sq  = rr.x * rr.x + rr.y * rr.y + rr.z * rr.z + rr.w * rr.w;

  #pragma unroll
  for (int off = 1; off < 64; off <<= 1) {
    sum += __shfl_xor(sum, off, 64);
    sq  += __shfl_xor(sq,  off, 64);
  }
  const int wid = tid >> 6;
  if ((tid & 63) == 0) { red[wid * 2] = sum; red[wid * 2 + 1] = sq; }
  __syncthreads();
  sum = red[0] + red[2] + red[4] + red[6];
  sq  = red[1] + red[3] + red[5] + red[7];

  const float mu   = sum * (1.f / (float)D_);
  const float var  = sq * (1.f / (float)D_) - mu * mu;
  const float rstd = rsqrtf(var + 1e-5f);

  float4 gg = *(const float4*)&g[d];
  float4 bb = *(const float4*)&beta[d];
  float4 o = { (rr.x - mu) * rstd * gg.x + bb.x,
               (rr.y - mu) * rstd * gg.y + bb.y,
               (rr.z - mu) * rstd * gg.z + bb.z,
               (rr.w - mu) * rstd * gg.w + bb.w };
  *(float4*)&out[(size_t)row * D_ + d] = o;
}

// ---------------------------------------------------------------------------
extern "C" void kernel_launch(void* const* d_in, const int* in_sizes, int n_in,
                              void* d_out, int out_size, void* d_ws, size_t ws_size,
                              hipStream_t stream) {
  const float* E    = (const float*)d_in[0];
  const float* Ev   = (const float*)d_in[1];
  const float* R    = (const float*)d_in[2];
  const float* Wq   = (const float*)d_in[3];
  const float* Wke  = (const float*)d_in[4];
  const float* Wkr  = (const float*)d_in[5];
  const float* Wv   = (const float*)d_in[6];
  const float* cb   = (const float*)d_in[7];
  const float* pb   = (const float*)d_in[8];
  const float* Wo_w = (const float*)d_in[9];
  const float* Wo_b = (const float*)d_in[10];
  const float* ln_g = (const float*)d_in[11];
  const float* ln_b = (const float*)d_in[12];
  float* out = (float*)d_out;

  // Workspace layout (floats): q,k,v (2M each), Qp (1M), O (2M), proj (2M) = 44 MB
  const size_t M2 = (size_t)B_ * L_ * D_;   // 2M
  float* ws   = (float*)d_ws;
  float* q    = ws;
  float* kk   = ws + M2;
  float* vv   = ws + 2 * M2;
  float* Qp   = ws + 3 * M2;
  float* O    = ws + 3 * M2 + (size_t)L_ * D_;
  float* proj = O + M2;

  // 1) projections (q,k,v,Qp) in one z-batched launch
  dim3 g1(D_ / 128, (B_ * L_) / 128, 4);
  proj_gemm<<<g1, 256, 0, stream>>>(E, Ev, R, Wq, Wke, Wkr, Wv, q, kk, vv, Qp);

  // 2) attention
  attn_kernel<<<B_ * H_ * (L_ / RT), 256, 0, stream>>>(q, kk, vv, Qp, cb, pb, O);

  // 3) output projection
  gemm_out<<<dim3(D_ / 64, (B_ * L_) / 64), 256, 0, stream>>>(O, Wo_w, proj);

  // 4) residual + LayerNorm
  ln_kernel<<<B_ * L_, 256, 0, stream>>>(Ev, proj, Wo_b, ln_g, ln_b, out);
}

// Round 3
// 240.041 us; speedup vs baseline: 4.2976x; 4.2976x over previous
//
#include <hip/hip_runtime.h>
#include <hip/hip_bf16.h>
#include <math.h>

#define B_ 2
#define L_ 1024
#define D_ 1024
#define H_ 16

typedef short short8 __attribute__((ext_vector_type(8)));
typedef float f32x4  __attribute__((ext_vector_type(4)));

__device__ __forceinline__ short f2bf(float f) {
  unsigned u = __float_as_uint(f);
  u += 0x7fff + ((u >> 16) & 1);          // RNE
  return (short)(u >> 16);
}
__device__ __forceinline__ float bf2f(short s) {
  return __uint_as_float(((unsigned)(unsigned short)s) << 16);
}
// XOR-swizzled LDS index (in shorts) for [rows][64] bf16 tiles (128B rows):
// 16B slot `slot` of row `row` -> spreads b128 lane reads across banks (G4/T2).
__device__ __forceinline__ int swz(int row, int slot) {
  return row * 64 + ((slot ^ (row & 7)) << 3);
}

// ---------------------------------------------------------------------------
// bf16 MFMA GEMM: C[M,N] = A[M,K] @ Bt[N,K]^T. 128x128 tile, BK=64, 4 waves.
// A: fp32 (A_BF16=0) or bf16 (A_BF16=1). C: bf16 (OUT_F32=0) or fp32.
// ---------------------------------------------------------------------------
template<int A_BF16, int OUT_F32>
__device__ __forceinline__ void mm128_body(const void* Ap, const short* Bt,
                                           void* Cp, int N, int K,
                                           int bx, int by) {
  __shared__ short As[8192];
  __shared__ short Bs[8192];
  const int tid = threadIdx.x;
  const int l = tid & 63, w = tid >> 6;
  const int row0 = by * 128, col0 = bx * 128;
  const int wm = (w >> 1) * 64, wn = (w & 1) * 64;
  const f32x4 fz = {0.f, 0.f, 0.f, 0.f};

  f32x4 acc[4][4];
  #pragma unroll
  for (int i = 0; i < 4; ++i)
    #pragma unroll
    for (int j = 0; j < 4; ++j) acc[i][j] = fz;

  int crow[4], cslot[4];
  #pragma unroll
  for (int c = 0; c < 4; ++c) { int ci = tid + c * 256; crow[c] = ci >> 3; cslot[c] = ci & 7; }

  float4 af[4][2];
  short8 ab[4];
  short8 bb[4];

  auto loadT = [&](int k0) {
    #pragma unroll
    for (int c = 0; c < 4; ++c) {
      if (A_BF16) {
        ab[c] = *(const short8*)&((const short*)Ap)[(size_t)(row0 + crow[c]) * K + k0 + cslot[c] * 8];
      } else {
        const float* ap = &((const float*)Ap)[(size_t)(row0 + crow[c]) * K + k0 + cslot[c] * 8];
        af[c][0] = *(const float4*)ap;
        af[c][1] = *(const float4*)(ap + 4);
      }
      bb[c] = *(const short8*)&Bt[(size_t)(col0 + crow[c]) * K + k0 + cslot[c] * 8];
    }
  };
  auto writeT = [&]() {
    #pragma unroll
    for (int c = 0; c < 4; ++c) {
      short8 av;
      if (A_BF16) {
        av = ab[c];
      } else {
        av[0] = f2bf(af[c][0].x); av[1] = f2bf(af[c][0].y);
        av[2] = f2bf(af[c][0].z); av[3] = f2bf(af[c][0].w);
        av[4] = f2bf(af[c][1].x); av[5] = f2bf(af[c][1].y);
        av[6] = f2bf(af[c][1].z); av[7] = f2bf(af[c][1].w);
      }
      *(short8*)&As[swz(crow[c], cslot[c])] = av;
      *(short8*)&Bs[swz(crow[c], cslot[c])] = bb[c];
    }
  };

  const int nt = K / 64;
  loadT(0); writeT(); __syncthreads();

  for (int t = 0; t < nt; ++t) {
    if (t + 1 < nt) loadT((t + 1) * 64);
    #pragma unroll
    for (int kf = 0; kf < 2; ++kf) {
      short8 a[4], b[4];
      #pragma unroll
      for (int mf = 0; mf < 4; ++mf)
        a[mf] = *(const short8*)&As[swz(wm + mf * 16 + (l & 15), kf * 4 + (l >> 4))];
      #pragma unroll
      for (int nf = 0; nf < 4; ++nf)
        b[nf] = *(const short8*)&Bs[swz(wn + nf * 16 + (l & 15), kf * 4 + (l >> 4))];
      #pragma unroll
      for (int mf = 0; mf < 4; ++mf)
        #pragma unroll
        for (int nf = 0; nf < 4; ++nf)
          acc[mf][nf] = __builtin_amdgcn_mfma_f32_16x16x32_bf16(a[mf], b[nf], acc[mf][nf], 0, 0, 0);
    }
    if (t + 1 < nt) { __syncthreads(); writeT(); __syncthreads(); }
  }

  #pragma unroll
  for (int mf = 0; mf < 4; ++mf)
    #pragma unroll
    for (int nf = 0; nf < 4; ++nf)
      #pragma unroll
      for (int r = 0; r < 4; ++r) {
        int row = row0 + wm + mf * 16 + (l >> 4) * 4 + r;
        int col = col0 + wn + nf * 16 + (l & 15);
        if (OUT_F32) ((float*)Cp)[(size_t)row * N + col] = acc[mf][nf][r];
        else         ((short*)Cp)[(size_t)row * N + col] = f2bf(acc[mf][nf][r]);
      }
}

// z=0: q=E@Wq ; z=1: k=Ev@Wke ; z=2: v=Ev@Wv ; z=3: Qp=R@Wkr. Outputs bf16.
__global__ __launch_bounds__(256) void proj_mfma(
    const float* __restrict__ E, const float* __restrict__ Ev, const float* __restrict__ R,
    const short* __restrict__ Wt,
    short* __restrict__ qb, short* __restrict__ kb,
    short* __restrict__ vb, short* __restrict__ Qpb) {
  const int z = blockIdx.z;
  const void* A; const short* Bt; void* C; int M;
  const size_t MM = (size_t)D_ * D_;
  if (z == 0)      { A = E;  Bt = Wt;          C = qb;  M = B_ * L_; }
  else if (z == 1) { A = Ev; Bt = Wt + MM;     C = kb;  M = B_ * L_; }
  else if (z == 2) { A = Ev; Bt = Wt + 3 * MM; C = vb;  M = B_ * L_; }
  else             { A = R;  Bt = Wt + 2 * MM; C = Qpb; M = L_;      }
  if ((int)blockIdx.y * 128 >= M) return;
  mm128_body<0, 0>(A, Bt, C, D_, D_, blockIdx.x, blockIdx.y);
}

__global__ __launch_bounds__(256) void out_mfma(
    const short* __restrict__ Ob, const short* __restrict__ Wot, float* __restrict__ proj) {
  mm128_body<1, 1>(Ob, Wot, proj, D_, D_, blockIdx.x, blockIdx.y);
}

// ---------------------------------------------------------------------------
// Transpose + cast: Wt[z][n][k] = (float)W_z[k][n] -> bf16. 64x64 tiles.
// z order: Wq, Wke, Wkr, Wv, Wo_w
// ---------------------------------------------------------------------------
__global__ __launch_bounds__(256) void tcast(
    const float* __restrict__ W0, const float* __restrict__ W1,
    const float* __restrict__ W2, const float* __restrict__ W3,
    const float* __restrict__ W4, short* __restrict__ out) {
  const int z = blockIdx.z;
  const float* W = (z == 0) ? W0 : (z == 1) ? W1 : (z == 2) ? W2 : (z == 3) ? W3 : W4;
  short* Wt = out + (size_t)z * D_ * D_;
  __shared__ short t[64][65];
  const int tid = threadIdx.x;
  const int r0 = blockIdx.y * 64, c0 = blockIdx.x * 64;
  #pragma unroll
  for (int i = 0; i < 4; ++i) {
    int idx = tid + i * 256;
    int r = idx >> 4, c4 = (idx & 15) * 4;
    float4 v = *(const float4*)&W[(size_t)(r0 + r) * D_ + c0 + c4];
    t[c4 + 0][r] = f2bf(v.x); t[c4 + 1][r] = f2bf(v.y);
    t[c4 + 2][r] = f2bf(v.z); t[c4 + 3][r] = f2bf(v.w);
  }
  __syncthreads();
  #pragma unroll
  for (int i = 0; i < 2; ++i) {
    int idx = tid + i * 256;
    int rr = idx >> 3, cc = (idx & 7) * 8;
    short8 o;
    #pragma unroll
    for (int e = 0; e < 8; ++e) o[e] = t[rr][cc + e];
    *(short8*)&Wt[(size_t)(c0 + rr) * D_ + r0 + cc] = o;
  }
}

// ---------------------------------------------------------------------------
// cvec[b,h,j] = cb_h . k[b,j,h];  dvec[h,m] = pb_h . Qp[m,h]
// ---------------------------------------------------------------------------
__global__ __launch_bounds__(256) void cdvec(
    const short* __restrict__ kb, const short* __restrict__ Qpb,
    const float* __restrict__ cb, const float* __restrict__ pb,
    float* __restrict__ cvec, float* __restrict__ dvec) {
  int idx = blockIdx.x * 256 + threadIdx.x;
  if (idx < B_ * H_ * L_) {
    int b = idx >> 14, h = (idx >> 10) & 15, j = idx & 1023;
    const short* kr = &kb[(size_t)(b * L_ + j) * D_ + h * 64];
    const float* cr = &cb[h * 64];
    float s = 0.f;
    #pragma unroll
    for (int d8 = 0; d8 < 8; ++d8) {
      short8 kv = *(const short8*)&kr[d8 * 8];
      #pragma unroll
      for (int e = 0; e < 8; ++e) s += bf2f(kv[e]) * cr[d8 * 8 + e];
    }
    cvec[idx] = s;
  } else {
    int i2 = idx - B_ * H_ * L_;
    if (i2 < H_ * L_) {
      int h = i2 >> 10, m = i2 & 1023;
      const short* qr = &Qpb[(size_t)m * D_ + h * 64];
      const float* pr = &pb[h * 64];
      float s = 0.f;
      #pragma unroll
      for (int d8 = 0; d8 < 8; ++d8) {
        short8 qv = *(const short8*)&qr[d8 * 8];
        #pragma unroll
        for (int e = 0; e < 8; ++e) s += bf2f(qv[e]) * pr[d8 * 8 + e];
      }
      dvec[i2] = s;
    }
  }
}

// ---------------------------------------------------------------------------
// MFMA attention. Block = 64 q-rows of one (b,h); 4 waves x 16-row strips.
// S = q.k + cvec[j] + mask*(q.Qp[m] + dvec[m]), m = L-1-i+j; full softmax.
// ---------------------------------------------------------------------------
__global__ __launch_bounds__(256) void attn_mfma(
    const short* __restrict__ qb, const short* __restrict__ kb,
    const short* __restrict__ vb, const short* __restrict__ Qpb,
    const float* __restrict__ cvec, const float* __restrict__ dvec,
    short* __restrict__ Ob) {
  __shared__ short q_s[4096];
  __shared__ short k_s[4096];
  __shared__ short vt_s[4096];
  __shared__ short win_s[8192];
  __shared__ short pb_s[4 * 1312];   // per-wave: Pb[16][82] ; P[16][64] overlay
  __shared__ float cvec_s[64];
  __shared__ float dvec_s[128];

  const int tid = threadIdx.x;
  const int l = tid & 63, w = tid >> 6;
  const int nib = L_ / 64;
  const int b  = blockIdx.x / (H_ * nib);
  const int hh = (blockIdx.x / nib) % H_;
  const int i0 = (blockIdx.x % nib) * 64;
  const f32x4 fz = {0.f, 0.f, 0.f, 0.f};

  #pragma unroll
  for (int c = 0; c < 2; ++c) {
    int ci = tid + c * 256;
    int r = ci >> 3, s = ci & 7;
    *(short8*)&q_s[swz(r, s)] =
        *(const short8*)&qb[(size_t)(b * L_ + i0 + r) * D_ + hh * 64 + s * 8];
  }
  __syncthreads();

  short8 aq[2];
  {
    int row = w * 16 + (l & 15);
    aq[0] = *(const short8*)&q_s[swz(row, (l >> 4))];
    aq[1] = *(const short8*)&q_s[swz(row, 4 + (l >> 4))];
  }

  float mrow[4], lrow[4];
  f32x4 oacc[4];
  #pragma unroll
  for (int r = 0; r < 4; ++r) { mrow[r] = -3.0e38f; lrow[r] = 0.f; }
  #pragma unroll
  for (int nf = 0; nf < 4; ++nf) oacc[nf] = fz;

  for (int jt = 0; jt < 16; ++jt) {
    const int j0 = jt * 64;
    const bool pos = (j0 <= i0);
    const bool diag = (j0 == i0);
    const int mbase = L_ - 64 - i0 + j0;

    __syncthreads();   // previous tile's LDS reads complete

    #pragma unroll
    for (int c = 0; c < 2; ++c) {
      int ci = tid + c * 256;
      int r = ci >> 3, s = ci & 7;
      *(short8*)&k_s[swz(r, s)] =
          *(const short8*)&kb[(size_t)(b * L_ + j0 + r) * D_ + hh * 64 + s * 8];
    }
    #pragma unroll
    for (int c = 0; c < 2; ++c) {
      int ci = tid + c * 256;
      int jr = ci >> 3, s = ci & 7;
      short8 vv = *(const short8*)&vb[(size_t)(b * L_ + j0 + jr) * D_ + hh * 64 + s * 8];
      #pragma unroll
      for (int e = 0; e < 8; ++e) {
        int d = s * 8 + e;
        vt_s[d * 64 + (((jr >> 3) ^ (d & 7)) << 3) + (jr & 7)] = vv[e];
      }
    }
    if (tid < 64) cvec_s[tid] = cvec[(size_t)(b * H_ + hh) * L_ + j0 + tid];
    if (pos) {
      #pragma unroll
      for (int c = 0; c < 4; ++c) {
        int ci = tid + c * 256;
        int mm = ci >> 3, s = ci & 7;
        int m = mbase + mm;
        short8 wv = {0, 0, 0, 0, 0, 0, 0, 0};
        if (m < L_) wv = *(const short8*)&Qpb[(size_t)m * D_ + hh * 64 + s * 8];
        *(short8*)&win_s[swz(mm, s)] = wv;
      }
      if (tid < 128) {
        int m = mbase + tid;
        dvec_s[tid] = (m < L_) ? dvec[hh * L_ + m] : 0.f;
      }
    }
    __syncthreads();

    // QK^T
    f32x4 sac[4];
    #pragma unroll
    for (int nf = 0; nf < 4; ++nf) sac[nf] = fz;
    #pragma unroll
    for (int kf = 0; kf < 2; ++kf) {
      #pragma unroll
      for (int nf = 0; nf < 4; ++nf) {
        short8 bk = *(const short8*)&k_s[swz(nf * 16 + (l & 15), kf * 4 + (l >> 4))];
        sac[nf] = __builtin_amdgcn_mfma_f32_16x16x32_bf16(aq[kf], bk, sac[nf], 0, 0, 0);
      }
    }

    // positional GEMM over the 80-col per-wave subwindow
    if (pos) {
      f32x4 pacc[5];
      #pragma unroll
      for (int u = 0; u < 5; ++u) pacc[u] = fz;
      const int nf0 = 3 - w;
      #pragma unroll
      for (int kf = 0; kf < 2; ++kf) {
        #pragma unroll
        for (int u = 0; u < 5; ++u) {
          short8 bw = *(const short8*)&win_s[swz((nf0 + u) * 16 + (l & 15), kf * 4 + (l >> 4))];
          pacc[u] = __builtin_amdgcn_mfma_f32_16x16x32_bf16(aq[kf], bw, pacc[u], 0, 0, 0);
        }
      }
      const int pbb = w * 1312;
      #pragma unroll
      for (int u = 0; u < 5; ++u)
        #pragma unroll
        for (int r = 0; r < 4; ++r) {
          int row = (l >> 4) * 4 + r;
          pb_s[pbb + row * 82 + u * 16 + (l & 15)] = f2bf(pacc[u][r]);
        }
    }

    // biases + shifted positional gather
    #pragma unroll
    for (int nf = 0; nf < 4; ++nf)
      #pragma unroll
      for (int r = 0; r < 4; ++r) {
        int rj = nf * 16 + (l & 15);
        float s = sac[nf][r] + cvec_s[rj];
        if (pos) {
          int ris = (l >> 4) * 4 + r;     // row within strip
          int rib = w * 16 + ris;         // row within block
          if (!diag || rj <= rib) {
            s += bf2f(pb_s[w * 1312 + ris * 82 + (15 - ris + rj)]);
            s += dvec_s[63 - rib + rj];
          }
        }
        sac[nf][r] = s;
      }

    // online softmax (16-lane row groups)
    #pragma unroll
    for (int r = 0; r < 4; ++r) {
      float mx = fmaxf(fmaxf(sac[0][r], sac[1][r]), fmaxf(sac[2][r], sac[3][r]));
      #pragma unroll
      for (int off = 1; off < 16; off <<= 1)
        mx = fmaxf(mx, __shfl_xor(mx, off, 64));
      float mn = fmaxf(mrow[r], mx);
      float sc = __expf(mrow[r] - mn);
      mrow[r] = mn;
      float ls = 0.f;
      #pragma unroll
      for (int nf = 0; nf < 4; ++nf) {
        float p = __expf(sac[nf][r] - mn);
        sac[nf][r] = p;
        ls += p;
      }
      #pragma unroll
      for (int off = 1; off < 16; off <<= 1)
        ls += __shfl_xor(ls, off, 64);
      lrow[r] = lrow[r] * sc + ls;
      #pragma unroll
      for (int nf = 0; nf < 4; ++nf) oacc[nf][r] *= sc;
    }

    // P -> bf16 in wave-private LDS (overlays Pb; same-wave program order)
    #pragma unroll
    for (int nf = 0; nf < 4; ++nf)
      #pragma unroll
      for (int r = 0; r < 4; ++r) {
        int row = (l >> 4) * 4 + r;
        int col = nf * 16 + (l & 15);
        pb_s[w * 1312 + row * 64 + (((col >> 3) ^ (row & 7)) << 3) + (col & 7)] = f2bf(sac[nf][r]);
      }

    // PV
    #pragma unroll
    for (int kf = 0; kf < 2; ++kf) {
      int prow = l & 15;
      short8 ap = *(const short8*)&pb_s[w * 1312 + prow * 64 + (((kf * 4 + (l >> 4)) ^ (prow & 7)) << 3)];
      #pragma unroll
      for (int nf = 0; nf < 4; ++nf) {
        short8 bv = *(const short8*)&vt_s[swz(nf * 16 + (l & 15), kf * 4 + (l >> 4))];
        oacc[nf] = __builtin_amdgcn_mfma_f32_16x16x32_bf16(ap, bv, oacc[nf], 0, 0, 0);
      }
    }
  }

  #pragma unroll
  for (int nf = 0; nf < 4; ++nf)
    #pragma unroll
    for (int r = 0; r < 4; ++r) {
      int row = i0 + w * 16 + (l >> 4) * 4 + r;
      int col = hh * 64 + nf * 16 + (l & 15);
      Ob[(size_t)(b * L_ + row) * D_ + col] = f2bf(oacc[nf][r] / lrow[r]);
    }
}

// ---------------------------------------------------------------------------
// res = Ev + proj + Wo_b; LayerNorm * g + b. One block per row.
// ---------------------------------------------------------------------------
__global__ __launch_bounds__(256) void ln_kernel(
    const float* __restrict__ Ev, const float* __restrict__ proj,
    const float* __restrict__ Wo_b, const float* __restrict__ g,
    const float* __restrict__ beta, float* __restrict__ out) {
  const int row = blockIdx.x;
  __shared__ float red[8];
  const int tid = threadIdx.x;
  const int d = tid * 4;

  float4 e  = *(const float4*)&Ev[(size_t)row * D_ + d];
  float4 p  = *(const float4*)&proj[(size_t)row * D_ + d];
  float4 wb = *(const float4*)&Wo_b[d];
  float4 rr = { e.x + p.x + wb.x, e.y + p.y + wb.y,
                e.z + p.z + wb.z, e.w + p.w + wb.w };
  float sum = rr.x + rr.y + rr.z + rr.w;
  float sq  = rr.x * rr.x + rr.y * rr.y + rr.z * rr.z + rr.w * rr.w;

  #pragma unroll
  for (int off = 1; off < 64; off <<= 1) {
    sum += __shfl_xor(sum, off, 64);
    sq  += __shfl_xor(sq,  off, 64);
  }
  const int wid = tid >> 6;
  if ((tid & 63) == 0) { red[wid * 2] = sum; red[wid * 2 + 1] = sq; }
  __syncthreads();
  sum = red[0] + red[2] + red[4] + red[6];
  sq  = red[1] + red[3] + red[5] + red[7];

  const float mu   = sum * (1.f / (float)D_);
  const float var  = sq * (1.f / (float)D_) - mu * mu;
  const float rstd = rsqrtf(var + 1e-5f);

  float4 gg = *(const float4*)&g[d];
  float4 bb = *(const float4*)&beta[d];
  float4 o = { (rr.x - mu) * rstd * gg.x + bb.x,
               (rr.y - mu) * rstd * gg.y + bb.y,
               (rr.z - mu) * rstd * gg.z + bb.z,
               (rr.w - mu) * rstd * gg.w + bb.w };
  *(float4*)&out[(size_t)row * D_ + d] = o;
}

// ---------------------------------------------------------------------------
extern "C" void kernel_launch(void* const* d_in, const int* in_sizes, int n_in,
                              void* d_out, int out_size, void* d_ws, size_t ws_size,
                              hipStream_t stream) {
  const float* E    = (const float*)d_in[0];
  const float* Ev   = (const float*)d_in[1];
  const float* R    = (const float*)d_in[2];
  const float* Wq   = (const float*)d_in[3];
  const float* Wke  = (const float*)d_in[4];
  const float* Wkr  = (const float*)d_in[5];
  const float* Wv   = (const float*)d_in[6];
  const float* cb   = (const float*)d_in[7];
  const float* pb   = (const float*)d_in[8];
  const float* Wo_w = (const float*)d_in[9];
  const float* Wo_b = (const float*)d_in[10];
  const float* ln_g = (const float*)d_in[11];
  const float* ln_b = (const float*)d_in[12];
  float* out = (float*)d_out;

  // Workspace (shorts unless noted): q 2M | k 2M | v 2M | Qp 1M | Wt 5M | O 2M
  // then proj (2M floats) | cvec (32K f) | dvec (16K f)  => ~36.2 MB total
  short* qb   = (short*)d_ws;
  short* kb   = qb + 2097152;
  short* vb   = kb + 2097152;
  short* Qpb  = vb + 2097152;
  short* Wt   = Qpb + 1048576;
  short* Ob   = Wt + 5242880;
  float* proj = (float*)(Ob + 2097152);
  float* cvec = proj + 2097152;
  float* dvec = cvec + 32768;

  // 1) transpose+cast weights (z: Wq, Wke, Wkr, Wv, Wo_w)
  tcast<<<dim3(16, 16, 5), 256, 0, stream>>>(Wq, Wke, Wkr, Wv, Wo_w, Wt);

  // 2) projections -> bf16 q,k,v,Qp
  proj_mfma<<<dim3(8, 16, 4), 256, 0, stream>>>(E, Ev, R, Wt, qb, kb, vb, Qpb);

  // 3) bias scalars
  cdvec<<<192, 256, 0, stream>>>(kb, Qpb, cb, pb, cvec, dvec);

  // 4) attention -> bf16 O
  attn_mfma<<<B_ * H_ * (L_ / 64), 256, 0, stream>>>(qb, kb, vb, Qpb, cvec, dvec, Ob);

  // 5) output projection -> fp32 proj
  out_mfma<<<dim3(8, 16), 256, 0, stream>>>(Ob, Wt + 4 * (size_t)D_ * D_, proj);

  // 6) residual + LayerNorm
  ln_kernel<<<B_ * L_, 256, 0, stream>>>(Ev, proj, Wo_b, ln_g, ln_b, out);
}

// Round 4
// 227.011 us; speedup vs baseline: 4.5443x; 1.0574x over previous
//
#include <hip/hip_runtime.h>
#include <hip/hip_bf16.h>
#include <math.h>

#define B_ 2
#define L_ 1024
#define D_ 1024
#define H_ 16

typedef short short8 __attribute__((ext_vector_type(8)));
typedef float f32x4  __attribute__((ext_vector_type(4)));

__device__ __forceinline__ short f2bf(float f) {
  unsigned u = __float_as_uint(f);
  u += 0x7fff + ((u >> 16) & 1);          // RNE
  return (short)(u >> 16);
}
__device__ __forceinline__ float bf2f(short s) {
  return __uint_as_float(((unsigned)(unsigned short)s) << 16);
}
// XOR-swizzled LDS index (shorts) for [rows][64] bf16 tiles.
__device__ __forceinline__ int swz(int row, int slot) {
  return row * 64 + ((slot ^ (row & 7)) << 3);
}
// V^T tile swizzle: includes d>>3 so transpose WRITES spread over all banks.
__device__ __forceinline__ int vswz(int d, int j) {
  return d * 64 + ((((j >> 3) ^ (d & 7) ^ ((d >> 3) & 7)) & 7) << 3) + (j & 7);
}

// global -> LDS direct (16B per lane, wave-uniform LDS base)
__device__ __forceinline__ void glds16(const void* g, void* l) {
  __builtin_amdgcn_global_load_lds((const __attribute__((address_space(1))) void*)g,
                                   (__attribute__((address_space(3))) void*)l, 16, 0, 0);
}

// ---------------------------------------------------------------------------
// cast E(2M), Ev(2M), R(1M) fp32 -> bf16 contiguous at o
// ---------------------------------------------------------------------------
__global__ __launch_bounds__(256) void castbf(
    const float* __restrict__ E, const float* __restrict__ Ev,
    const float* __restrict__ R, short* __restrict__ o) {
  size_t i8 = ((size_t)blockIdx.x * 256 + threadIdx.x) * 8;
  const float* src; size_t off;
  if (i8 < 2097152)      { src = E;  off = i8; }
  else if (i8 < 4194304) { src = Ev; off = i8 - 2097152; }
  else                   { src = R;  off = i8 - 4194304; }
  float4 a = *(const float4*)&src[off];
  float4 b = *(const float4*)&src[off + 4];
  short8 v;
  v[0] = f2bf(a.x); v[1] = f2bf(a.y); v[2] = f2bf(a.z); v[3] = f2bf(a.w);
  v[4] = f2bf(b.x); v[5] = f2bf(b.y); v[6] = f2bf(b.z); v[7] = f2bf(b.w);
  *(short8*)&o[i8] = v;
}

// ---------------------------------------------------------------------------
// m97-structure bf16 GEMM: C[M,N] = A[M,K] @ Bt[N,K]^T. 128x128, BK=64,
// 4 waves, global_load_lds(16B) staging into linear LDS, 2-barrier loop.
// ---------------------------------------------------------------------------
template<int OUT_F32>
__device__ __forceinline__ void mm_glds(const short* __restrict__ A,
                                        const short* __restrict__ Bt,
                                        void* Cp, int N, int K,
                                        int bx, int by) {
  __shared__ short As[8192];
  __shared__ short Bs[8192];
  const int tid = threadIdx.x;
  const int l = tid & 63, w = tid >> 6;
  const int row0 = by * 128, col0 = bx * 128;
  const int wm = (w >> 1) * 64, wn = (w & 1) * 64;
  const f32x4 fz = {0.f, 0.f, 0.f, 0.f};

  f32x4 acc[4][4];
  #pragma unroll
  for (int i = 0; i < 4; ++i)
    #pragma unroll
    for (int j = 0; j < 4; ++j) acc[i][j] = fz;

  const int lrow = l >> 3;          // 0..7 within 8-row chunk
  const int lcol = (l & 7) * 8;     // shorts

  for (int t = 0; t < K / 64; ++t) {
    const int k0 = t * 64;
    if (t) __syncthreads();
    #pragma unroll
    for (int c = 0; c < 4; ++c) {
      const int rr = (w * 4 + c) * 8 + lrow;
      glds16(&A[(size_t)(row0 + rr) * K + k0 + lcol], &As[(w * 4 + c) * 512]);
      glds16(&Bt[(size_t)(col0 + rr) * K + k0 + lcol], &Bs[(w * 4 + c) * 512]);
    }
    __syncthreads();   // drains vmcnt, then barrier
    #pragma unroll
    for (int kf = 0; kf < 2; ++kf) {
      short8 a[4], b[4];
      #pragma unroll
      for (int mf = 0; mf < 4; ++mf)
        a[mf] = *(const short8*)&As[(wm + mf * 16 + (l & 15)) * 64 + (kf * 4 + (l >> 4)) * 8];
      #pragma unroll
      for (int nf = 0; nf < 4; ++nf)
        b[nf] = *(const short8*)&Bs[(wn + nf * 16 + (l & 15)) * 64 + (kf * 4 + (l >> 4)) * 8];
      #pragma unroll
      for (int mf = 0; mf < 4; ++mf)
        #pragma unroll
        for (int nf = 0; nf < 4; ++nf)
          acc[mf][nf] = __builtin_amdgcn_mfma_f32_16x16x32_bf16(a[mf], b[nf], acc[mf][nf], 0, 0, 0);
    }
  }

  #pragma unroll
  for (int mf = 0; mf < 4; ++mf)
    #pragma unroll
    for (int nf = 0; nf < 4; ++nf)
      #pragma unroll
      for (int r = 0; r < 4; ++r) {
        int row = row0 + wm + mf * 16 + (l >> 4) * 4 + r;
        int col = col0 + wn + nf * 16 + (l & 15);
        if (OUT_F32) ((float*)Cp)[(size_t)row * N + col] = acc[mf][nf][r];
        else         ((short*)Cp)[(size_t)row * N + col] = f2bf(acc[mf][nf][r]);
      }
}

// z=0: q=Eb@Wq ; z=1: k=Evb@Wke ; z=2: v=Evb@Wv ; z=3: Qp=Rb@Wkr. Out bf16.
__global__ __launch_bounds__(256) void proj_mfma(
    const short* __restrict__ Eb, const short* __restrict__ Evb,
    const short* __restrict__ Rb, const short* __restrict__ Wt,
    short* __restrict__ qb, short* __restrict__ kb,
    short* __restrict__ vb, short* __restrict__ Qpb) {
  const int z = blockIdx.z;
  const short* A; const short* Bt; short* C; int M;
  const size_t MM = (size_t)D_ * D_;
  if (z == 0)      { A = Eb;  Bt = Wt;          C = qb;  M = B_ * L_; }
  else if (z == 1) { A = Evb; Bt = Wt + MM;     C = kb;  M = B_ * L_; }
  else if (z == 2) { A = Evb; Bt = Wt + 3 * MM; C = vb;  M = B_ * L_; }
  else             { A = Rb;  Bt = Wt + 2 * MM; C = Qpb; M = L_;      }
  if ((int)blockIdx.y * 128 >= M) return;
  mm_glds<0>(A, Bt, C, D_, D_, blockIdx.x, blockIdx.y);
}

__global__ __launch_bounds__(256) void out_mfma(
    const short* __restrict__ Ob, const short* __restrict__ Wot, float* __restrict__ proj) {
  mm_glds<1>(Ob, Wot, proj, D_, D_, blockIdx.x, blockIdx.y);
}

// ---------------------------------------------------------------------------
// Transpose + cast weights: Wt[z][n][k] = W_z[k][n] bf16. z: Wq,Wke,Wkr,Wv,Wo_w
// ---------------------------------------------------------------------------
__global__ __launch_bounds__(256) void tcast(
    const float* __restrict__ W0, const float* __restrict__ W1,
    const float* __restrict__ W2, const float* __restrict__ W3,
    const float* __restrict__ W4, short* __restrict__ out) {
  const int z = blockIdx.z;
  const float* W = (z == 0) ? W0 : (z == 1) ? W1 : (z == 2) ? W2 : (z == 3) ? W3 : W4;
  short* Wt = out + (size_t)z * D_ * D_;
  __shared__ short t[64][65];
  const int tid = threadIdx.x;
  const int r0 = blockIdx.y * 64, c0 = blockIdx.x * 64;
  #pragma unroll
  for (int i = 0; i < 4; ++i) {
    int idx = tid + i * 256;
    int r = idx >> 4, c4 = (idx & 15) * 4;
    float4 v = *(const float4*)&W[(size_t)(r0 + r) * D_ + c0 + c4];
    t[c4 + 0][r] = f2bf(v.x); t[c4 + 1][r] = f2bf(v.y);
    t[c4 + 2][r] = f2bf(v.z); t[c4 + 3][r] = f2bf(v.w);
  }
  __syncthreads();
  #pragma unroll
  for (int i = 0; i < 2; ++i) {
    int idx = tid + i * 256;
    int rr = idx >> 3, cc = (idx & 7) * 8;
    short8 o;
    #pragma unroll
    for (int e = 0; e < 8; ++e) o[e] = t[rr][cc + e];
    *(short8*)&Wt[(size_t)(c0 + rr) * D_ + r0 + cc] = o;
  }
}

// ---------------------------------------------------------------------------
// cvec[b,h,j] = cb_h . k[b,j,h];  dvec[h,m] = pb_h . Qp[m,h]
// ---------------------------------------------------------------------------
__global__ __launch_bounds__(256) void cdvec(
    const short* __restrict__ kb, const short* __restrict__ Qpb,
    const float* __restrict__ cb, const float* __restrict__ pb,
    float* __restrict__ cvec, float* __restrict__ dvec) {
  int idx = blockIdx.x * 256 + threadIdx.x;
  if (idx < B_ * H_ * L_) {
    int b = idx >> 14, h = (idx >> 10) & 15, j = idx & 1023;
    const short* kr = &kb[(size_t)(b * L_ + j) * D_ + h * 64];
    const float* cr = &cb[h * 64];
    float s = 0.f;
    #pragma unroll
    for (int d8 = 0; d8 < 8; ++d8) {
      short8 kv = *(const short8*)&kr[d8 * 8];
      #pragma unroll
      for (int e = 0; e < 8; ++e) s += bf2f(kv[e]) * cr[d8 * 8 + e];
    }
    cvec[idx] = s;
  } else {
    int i2 = idx - B_ * H_ * L_;
    if (i2 < H_ * L_) {
      int h = i2 >> 10, m = i2 & 1023;
      const short* qr = &Qpb[(size_t)m * D_ + h * 64];
      const float* pr = &pb[h * 64];
      float s = 0.f;
      #pragma unroll
      for (int d8 = 0; d8 < 8; ++d8) {
        short8 qv = *(const short8*)&qr[d8 * 8];
        #pragma unroll
        for (int e = 0; e < 8; ++e) s += bf2f(qv[e]) * pr[d8 * 8 + e];
      }
      dvec[i2] = s;
    }
  }
}

// ---------------------------------------------------------------------------
// MFMA attention with T14 async staging. Block = 64 q-rows of one (b,h).
// S = q.k + cvec[j] + mask*(q.Qp[m] + dvec[m]), m = L-1-i+j; full softmax.
// ---------------------------------------------------------------------------
__global__ __launch_bounds__(256) void attn_mfma(
    const short* __restrict__ qb, const short* __restrict__ kb,
    const short* __restrict__ vb, const short* __restrict__ Qpb,
    const float* __restrict__ cvec, const float* __restrict__ dvec,
    short* __restrict__ Ob) {
  __shared__ short q_s[4096];
  __shared__ short k_s[4096];
  __shared__ short vt_s[4096];
  __shared__ short win_s[8192];
  __shared__ short pb_s[4 * 1312];   // per-wave: Pb[16][82] ; P[16][64] overlay
  __shared__ float cvec_s[64];
  __shared__ float dvec_s[128];

  const int tid = threadIdx.x;
  const int l = tid & 63, w = tid >> 6;
  const int nib = L_ / 64;
  const int b  = blockIdx.x / (H_ * nib);
  const int hh = (blockIdx.x / nib) % H_;
  const int i0 = (blockIdx.x % nib) * 64;
  const f32x4 fz = {0.f, 0.f, 0.f, 0.f};
  const short8 sz = {0, 0, 0, 0, 0, 0, 0, 0};

  // prefetch registers (tile t+1 in flight while tile t computes)
  short8 rk[2], rv[2], rw[4];
  float rc = 0.f, rd = 0.f;

  auto stage_load = [&](int jt) {
    const int j0 = jt * 64;
    const bool pos = (j0 <= i0);
    const int mbase = L_ - 64 - i0 + j0;
    #pragma unroll
    for (int c = 0; c < 2; ++c) {
      int ci = tid + c * 256;
      int r = ci >> 3, s = ci & 7;
      rk[c] = *(const short8*)&kb[(size_t)(b * L_ + j0 + r) * D_ + hh * 64 + s * 8];
      rv[c] = *(const short8*)&vb[(size_t)(b * L_ + j0 + r) * D_ + hh * 64 + s * 8];
    }
    if (pos) {
      #pragma unroll
      for (int c = 0; c < 4; ++c) {
        int ci = tid + c * 256;
        int mm = ci >> 3, s = ci & 7;
        int m = mbase + mm;
        rw[c] = (m < L_) ? *(const short8*)&Qpb[(size_t)m * D_ + hh * 64 + s * 8] : sz;
      }
      if (tid < 128) {
        int m = mbase + tid;
        rd = (m < L_) ? dvec[hh * L_ + m] : 0.f;
      }
    }
    if (tid < 64) rc = cvec[(size_t)(b * H_ + hh) * L_ + j0 + tid];
  };

  auto stage_write = [&](int jt) {
    const bool pos = (jt * 64 <= i0);
    #pragma unroll
    for (int c = 0; c < 2; ++c) {
      int ci = tid + c * 256;
      int r = ci >> 3, s = ci & 7;
      *(short8*)&k_s[swz(r, s)] = rk[c];
      #pragma unroll
      for (int e = 0; e < 8; ++e) {
        int d = s * 8 + e;
        vt_s[vswz(d, r)] = rv[c][e];
      }
    }
    if (pos) {
      #pragma unroll
      for (int c = 0; c < 4; ++c) {
        int ci = tid + c * 256;
        int mm = ci >> 3, s = ci & 7;
        *(short8*)&win_s[swz(mm, s)] = rw[c];
      }
      if (tid < 128) dvec_s[tid] = rd;
    }
    if (tid < 64) cvec_s[tid] = rc;
  };

  // q staging + tile-0 prefetch
  short8 rq[2];
  #pragma unroll
  for (int c = 0; c < 2; ++c) {
    int ci = tid + c * 256;
    int r = ci >> 3, s = ci & 7;
    rq[c] = *(const short8*)&qb[(size_t)(b * L_ + i0 + r) * D_ + hh * 64 + s * 8];
  }
  stage_load(0);
  #pragma unroll
  for (int c = 0; c < 2; ++c) {
    int ci = tid + c * 256;
    *(short8*)&q_s[swz(ci >> 3, ci & 7)] = rq[c];
  }
  __syncthreads();

  short8 aq[2];
  {
    int row = w * 16 + (l & 15);
    aq[0] = *(const short8*)&q_s[swz(row, (l >> 4))];
    aq[1] = *(const short8*)&q_s[swz(row, 4 + (l >> 4))];
  }

  float mrow[4], lrow[4];
  f32x4 oacc[4];
  #pragma unroll
  for (int r = 0; r < 4; ++r) { mrow[r] = -3.0e38f; lrow[r] = 0.f; }
  #pragma unroll
  for (int nf = 0; nf < 4; ++nf) oacc[nf] = fz;

  for (int jt = 0; jt < 16; ++jt) {
    const int j0 = jt * 64;
    const bool pos = (j0 <= i0);
    const bool diag = (j0 == i0);

    stage_write(jt);
    __syncthreads();
    if (jt < 15) stage_load(jt + 1);   // T14: issue next-tile globals now

    // QK^T
    f32x4 sac[4];
    #pragma unroll
    for (int nf = 0; nf < 4; ++nf) sac[nf] = fz;
    #pragma unroll
    for (int kf = 0; kf < 2; ++kf) {
      #pragma unroll
      for (int nf = 0; nf < 4; ++nf) {
        short8 bk = *(const short8*)&k_s[swz(nf * 16 + (l & 15), kf * 4 + (l >> 4))];
        sac[nf] = __builtin_amdgcn_mfma_f32_16x16x32_bf16(aq[kf], bk, sac[nf], 0, 0, 0);
      }
    }

    // positional GEMM over the 80-col per-wave subwindow
    if (pos) {
      f32x4 pacc[5];
      #pragma unroll
      for (int u = 0; u < 5; ++u) pacc[u] = fz;
      const int nf0 = 3 - w;
      #pragma unroll
      for (int kf = 0; kf < 2; ++kf) {
        #pragma unroll
        for (int u = 0; u < 5; ++u) {
          short8 bw = *(const short8*)&win_s[swz((nf0 + u) * 16 + (l & 15), kf * 4 + (l >> 4))];
          pacc[u] = __builtin_amdgcn_mfma_f32_16x16x32_bf16(aq[kf], bw, pacc[u], 0, 0, 0);
        }
      }
      const int pbb = w * 1312;
      #pragma unroll
      for (int u = 0; u < 5; ++u)
        #pragma unroll
        for (int r = 0; r < 4; ++r) {
          int row = (l >> 4) * 4 + r;
          pb_s[pbb + row * 82 + u * 16 + (l & 15)] = f2bf(pacc[u][r]);
        }
    }

    // biases + shifted positional gather
    #pragma unroll
    for (int nf = 0; nf < 4; ++nf)
      #pragma unroll
      for (int r = 0; r < 4; ++r) {
        int rj = nf * 16 + (l & 15);
        float s = sac[nf][r] + cvec_s[rj];
        if (pos) {
          int ris = (l >> 4) * 4 + r;     // row within strip
          int rib = w * 16 + ris;         // row within block
          if (!diag || rj <= rib) {
            s += bf2f(pb_s[w * 1312 + ris * 82 + (15 - ris + rj)]);
            s += dvec_s[63 - rib + rj];
          }
        }
        sac[nf][r] = s;
      }

    // online softmax (16-lane row groups)
    #pragma unroll
    for (int r = 0; r < 4; ++r) {
      float mx = fmaxf(fmaxf(sac[0][r], sac[1][r]), fmaxf(sac[2][r], sac[3][r]));
      #pragma unroll
      for (int off = 1; off < 16; off <<= 1)
        mx = fmaxf(mx, __shfl_xor(mx, off, 64));
      float mn = fmaxf(mrow[r], mx);
      float sc = __expf(mrow[r] - mn);
      mrow[r] = mn;
      float ls = 0.f;
      #pragma unroll
      for (int nf = 0; nf < 4; ++nf) {
        float p = __expf(sac[nf][r] - mn);
        sac[nf][r] = p;
        ls += p;
      }
      #pragma unroll
      for (int off = 1; off < 16; off <<= 1)
        ls += __shfl_xor(ls, off, 64);
      lrow[r] = lrow[r] * sc + ls;
      #pragma unroll
      for (int nf = 0; nf < 4; ++nf) oacc[nf][r] *= sc;
    }

    // P -> bf16 in wave-private LDS (overlays Pb; same-wave program order)
    #pragma unroll
    for (int nf = 0; nf < 4; ++nf)
      #pragma unroll
      for (int r = 0; r < 4; ++r) {
        int row = (l >> 4) * 4 + r;
        int col = nf * 16 + (l & 15);
        pb_s[w * 1312 + row * 64 + (((col >> 3) ^ (row & 7)) << 3) + (col & 7)] = f2bf(sac[nf][r]);
      }

    // PV
    #pragma unroll
    for (int kf = 0; kf < 2; ++kf) {
      int prow = l & 15;
      short8 ap = *(const short8*)&pb_s[w * 1312 + prow * 64 + (((kf * 4 + (l >> 4)) ^ (prow & 7)) << 3)];
      #pragma unroll
      for (int nf = 0; nf < 4; ++nf) {
        short8 bv = *(const short8*)&vt_s[vswz(nf * 16 + (l & 15), (kf * 4 + (l >> 4)) * 8)];
        oacc[nf] = __builtin_amdgcn_mfma_f32_16x16x32_bf16(ap, bv, oacc[nf], 0, 0, 0);
      }
    }
    __syncthreads();
  }

  #pragma unroll
  for (int r = 0; r < 4; ++r) {
    float inv = 1.f / lrow[r];
    #pragma unroll
    for (int nf = 0; nf < 4; ++nf) {
      int row = i0 + w * 16 + (l >> 4) * 4 + r;
      int col = hh * 64 + nf * 16 + (l & 15);
      Ob[(size_t)(b * L_ + row) * D_ + col] = f2bf(oacc[nf][r] * inv);
    }
  }
}

// ---------------------------------------------------------------------------
// res = Ev + proj + Wo_b; LayerNorm * g + b. One block per row.
// ---------------------------------------------------------------------------
__global__ __launch_bounds__(256) void ln_kernel(
    const float* __restrict__ Ev, const float* __restrict__ proj,
    const float* __restrict__ Wo_b, const float* __restrict__ g,
    const float* __restrict__ beta, float* __restrict__ out) {
  const int row = blockIdx.x;
  __shared__ float red[8];
  const int tid = threadIdx.x;
  const int d = tid * 4;

  float4 e  = *(const float4*)&Ev[(size_t)row * D_ + d];
  float4 p  = *(const float4*)&proj[(size_t)row * D_ + d];
  float4 wb = *(const float4*)&Wo_b[d];
  float4 rr = { e.x + p.x + wb.x, e.y + p.y + wb.y,
                e.z + p.z + wb.z, e.w + p.w + wb.w };
  float sum = rr.x + rr.y + rr.z + rr.w;
  float sq  = rr.x * rr.x + rr.y * rr.y + rr.z * rr.z + rr.w * rr.w;

  #pragma unroll
  for (int off = 1; off < 64; off <<= 1) {
    sum += __shfl_xor(sum, off, 64);
    sq  += __shfl_xor(sq,  off, 64);
  }
  const int wid = tid >> 6;
  if ((tid & 63) == 0) { red[wid * 2] = sum; red[wid * 2 + 1] = sq; }
  __syncthreads();
  sum = red[0] + red[2] + red[4] + red[6];
  sq  = red[1] + red[3] + red[5] + red[7];

  const float mu   = sum * (1.f / (float)D_);
  const float var  = sq * (1.f / (float)D_) - mu * mu;
  const float rstd = rsqrtf(var + 1e-5f);

  float4 gg = *(const float4*)&g[d];
  float4 bb = *(const float4*)&beta[d];
  float4 o = { (rr.x - mu) * rstd * gg.x + bb.x,
               (rr.y - mu) * rstd * gg.y + bb.y,
               (rr.z - mu) * rstd * gg.z + bb.z,
               (rr.w - mu) * rstd * gg.w + bb.w };
  *(float4*)&out[(size_t)row * D_ + d] = o;
}

// ---------------------------------------------------------------------------
extern "C" void kernel_launch(void* const* d_in, const int* in_sizes, int n_in,
                              void* d_out, int out_size, void* d_ws, size_t ws_size,
                              hipStream_t stream) {
  const float* E    = (const float*)d_in[0];
  const float* Ev   = (const float*)d_in[1];
  const float* R    = (const float*)d_in[2];
  const float* Wq   = (const float*)d_in[3];
  const float* Wke  = (const float*)d_in[4];
  const float* Wkr  = (const float*)d_in[5];
  const float* Wv   = (const float*)d_in[6];
  const float* cb   = (const float*)d_in[7];
  const float* pb   = (const float*)d_in[8];
  const float* Wo_w = (const float*)d_in[9];
  const float* Wo_b = (const float*)d_in[10];
  const float* ln_g = (const float*)d_in[11];
  const float* ln_b = (const float*)d_in[12];
  float* out = (float*)d_out;

  // Workspace (shorts): Eb 2M | Evb 2M | Rb 1M | qb 2M | kb 2M | vb 2M |
  // Qpb 1M | Wt 5M | Ob 2M  = 19M shorts = 38 MB.
  // Aliases (stream-ordered safe): proj fp32 over Eb+Evb; cvec/dvec over Rb.
  short* ws   = (short*)d_ws;
  short* Eb   = ws;
  short* Evb  = ws + 2097152;
  short* Rb   = ws + 4194304;
  short* qb   = ws + 5242880;
  short* kb   = ws + 7340032;
  short* vb   = ws + 9437184;
  short* Qpb  = ws + 11534336;
  short* Wt   = ws + 12582912;
  short* Ob   = ws + 17825792;
  float* proj = (float*)Eb;          // used after Eb/Evb consumed
  float* cvec = (float*)Rb;          // used after Rb consumed
  float* dvec = cvec + 32768;

  // 1) cast activations to bf16
  castbf<<<2560, 256, 0, stream>>>(E, Ev, R, Eb);

  // 2) transpose+cast weights (z: Wq, Wke, Wkr, Wv, Wo_w)
  tcast<<<dim3(16, 16, 5), 256, 0, stream>>>(Wq, Wke, Wkr, Wv, Wo_w, Wt);

  // 3) projections -> bf16 q,k,v,Qp
  proj_mfma<<<dim3(8, 16, 4), 256, 0, stream>>>(Eb, Evb, Rb, Wt, qb, kb, vb, Qpb);

  // 4) bias scalars (Rb dead now; cvec/dvec overlay it)
  cdvec<<<192, 256, 0, stream>>>(kb, Qpb, cb, pb, cvec, dvec);

  // 5) attention -> bf16 O
  attn_mfma<<<B_ * H_ * (L_ / 64), 256, 0, stream>>>(qb, kb, vb, Qpb, cvec, dvec, Ob);

  // 6) output projection -> fp32 proj (Eb/Evb dead now)
  out_mfma<<<dim3(8, 16), 256, 0, stream>>>(Ob, Wt + 4 * (size_t)D_ * D_, proj);

  // 7) residual + LayerNorm
  ln_kernel<<<B_ * L_, 256, 0, stream>>>(Ev, proj, Wo_b, ln_g, ln_b, out);
}

// Round 5
// 217.628 us; speedup vs baseline: 4.7402x; 1.0431x over previous
//
#include <hip/hip_runtime.h>
#include <hip/hip_bf16.h>
#include <math.h>

#define B_ 2
#define L_ 1024
#define D_ 1024
#define H_ 16

typedef short short8 __attribute__((ext_vector_type(8)));
typedef float f32x4  __attribute__((ext_vector_type(4)));

__device__ __forceinline__ short f2bf(float f) {
  unsigned u = __float_as_uint(f);
  u += 0x7fff + ((u >> 16) & 1);          // RNE
  return (short)(u >> 16);
}
__device__ __forceinline__ float bf2f(short s) {
  return __uint_as_float(((unsigned)(unsigned short)s) << 16);
}
// XOR-swizzled LDS index (shorts) for [rows][64] bf16 tiles (16B slots).
__device__ __forceinline__ int swz(int row, int slot) {
  return row * 64 + (((slot ^ row) & 7) << 3);
}
// V^T tile swizzle (R4-verified: conflicts 8.6e6 -> 2.3e6)
__device__ __forceinline__ int vswz(int d, int j) {
  return d * 64 + ((((j >> 3) ^ (d & 7) ^ ((d >> 3) & 7)) & 7) << 3) + (j & 7);
}
// P-tile XOR key: distinct per row-group mod 4 AND rows 0-7/8-15 -> 2-way max
__device__ __forceinline__ int pkey(int row) {
  return (row & 7) ^ ((row & 8) >> 2);
}

// global -> LDS direct (16B/lane; LDS dest = wave-uniform base + lane*16)
__device__ __forceinline__ void glds16(const void* g, void* l) {
  __builtin_amdgcn_global_load_lds((const __attribute__((address_space(1))) void*)g,
                                   (__attribute__((address_space(3))) void*)l, 16, 0, 0);
}

// ---------------------------------------------------------------------------
// prep: (a) cast E,Ev,R -> bf16 contiguous; (b) transpose+cast 5 weights.
// ---------------------------------------------------------------------------
__global__ __launch_bounds__(256) void prep(
    const float* __restrict__ E, const float* __restrict__ Ev,
    const float* __restrict__ R,
    const float* __restrict__ W0, const float* __restrict__ W1,
    const float* __restrict__ W2, const float* __restrict__ W3,
    const float* __restrict__ W4,
    short* __restrict__ act, short* __restrict__ Wt) {
  __shared__ short t[64][65];
  const int tid = threadIdx.x;
  int bid = blockIdx.x;
  if (bid < 2560) {
    size_t i8 = ((size_t)bid * 256 + tid) * 8;
    const float* src; size_t off;
    if (i8 < 2097152)      { src = E;  off = i8; }
    else if (i8 < 4194304) { src = Ev; off = i8 - 2097152; }
    else                   { src = R;  off = i8 - 4194304; }
    float4 a = *(const float4*)&src[off];
    float4 b = *(const float4*)&src[off + 4];
    short8 v;
    v[0] = f2bf(a.x); v[1] = f2bf(a.y); v[2] = f2bf(a.z); v[3] = f2bf(a.w);
    v[4] = f2bf(b.x); v[5] = f2bf(b.y); v[6] = f2bf(b.z); v[7] = f2bf(b.w);
    *(short8*)&act[i8] = v;
    return;
  }
  bid -= 2560;
  const int z = bid >> 8, rem = bid & 255;
  const int by = rem >> 4, bx = rem & 15;
  const float* W = (z == 0) ? W0 : (z == 1) ? W1 : (z == 2) ? W2 : (z == 3) ? W3 : W4;
  short* Wtz = Wt + (size_t)z * D_ * D_;
  const int r0 = by * 64, c0 = bx * 64;
  #pragma unroll
  for (int i = 0; i < 4; ++i) {
    int idx = tid + i * 256;
    int r = idx >> 4, c4 = (idx & 15) * 4;
    float4 v = *(const float4*)&W[(size_t)(r0 + r) * D_ + c0 + c4];
    t[c4 + 0][r] = f2bf(v.x); t[c4 + 1][r] = f2bf(v.y);
    t[c4 + 2][r] = f2bf(v.z); t[c4 + 3][r] = f2bf(v.w);
  }
  __syncthreads();
  #pragma unroll
  for (int i = 0; i < 2; ++i) {
    int idx = tid + i * 256;
    int rr = idx >> 3, cc = (idx & 7) * 8;
    short8 o;
    #pragma unroll
    for (int e = 0; e < 8; ++e) o[e] = t[rr][cc + e];
    *(short8*)&Wtz[(size_t)(c0 + rr) * D_ + r0 + cc] = o;
  }
}

// ---------------------------------------------------------------------------
// bf16 MFMA GEMM, 64 x (NF*32) tile, BK=64, 4 waves (wave tile 32 x NF*16).
// glds(16B) into LINEAR LDS with pre-swizzled global source column; ds_read
// uses swz() -> conflict-free (rule 21: both-sides-or-neither).
// ---------------------------------------------------------------------------
template<int NF, int OUT_F32>
__device__ __forceinline__ void mm_nf(const short* __restrict__ A,
                                      const short* __restrict__ Bt,
                                      void* Cp, int N, int K, int bx, int by) {
  constexpr int BN = NF * 32;
  __shared__ short As[4096];
  __shared__ short Bs[BN * 64];
  const int tid = threadIdx.x;
  const int l = tid & 63, w = tid >> 6;
  const int row0 = by * 64, col0 = bx * BN;
  const int wm = (w >> 1) * 32, wn = (w & 1) * (NF * 16);
  const int lr = l >> 3;                    // row-in-chunk 0..7
  const int lc = ((l & 7) ^ lr) * 8;        // inverse-swizzled source slot
  const f32x4 fz = {0.f, 0.f, 0.f, 0.f};

  f32x4 acc[2][NF];
  #pragma unroll
  for (int i = 0; i < 2; ++i)
    #pragma unroll
    for (int j = 0; j < NF; ++j) acc[i][j] = fz;

  for (int t = 0; t < K / 64; ++t) {
    const int k0 = t * 64;
    if (t) __syncthreads();
    #pragma unroll
    for (int c = 0; c < 2; ++c) {
      int ch = w * 2 + c;
      glds16(&A[(size_t)(row0 + ch * 8 + lr) * K + k0 + lc], &As[ch * 512]);
    }
    #pragma unroll
    for (int c = 0; c < NF; ++c) {
      int ch = w * NF + c;
      glds16(&Bt[(size_t)(col0 + ch * 8 + lr) * K + k0 + lc], &Bs[ch * 512]);
    }
    __syncthreads();   // drains vmcnt then barrier
    #pragma unroll
    for (int kf = 0; kf < 2; ++kf) {
      const int slot = kf * 4 + (l >> 4);
      short8 a[2], b[NF];
      #pragma unroll
      for (int mf = 0; mf < 2; ++mf)
        a[mf] = *(const short8*)&As[swz(wm + mf * 16 + (l & 15), slot)];
      #pragma unroll
      for (int nf = 0; nf < NF; ++nf)
        b[nf] = *(const short8*)&Bs[swz(wn + nf * 16 + (l & 15), slot)];
      #pragma unroll
      for (int mf = 0; mf < 2; ++mf)
        #pragma unroll
        for (int nf = 0; nf < NF; ++nf)
          acc[mf][nf] = __builtin_amdgcn_mfma_f32_16x16x32_bf16(a[mf], b[nf], acc[mf][nf], 0, 0, 0);
    }
  }

  #pragma unroll
  for (int mf = 0; mf < 2; ++mf)
    #pragma unroll
    for (int nf = 0; nf < NF; ++nf)
      #pragma unroll
      for (int r = 0; r < 4; ++r) {
        int row = row0 + wm + mf * 16 + (l >> 4) * 4 + r;
        int col = col0 + wn + nf * 16 + (l & 15);
        if (OUT_F32) ((float*)Cp)[(size_t)row * N + col] = acc[mf][nf][r];
        else         ((short*)Cp)[(size_t)row * N + col] = f2bf(acc[mf][nf][r]);
      }
}

// z=0: q=Eb@Wq ; z=1: k=Evb@Wke ; z=2: v=Evb@Wv ; z=3: Qp=Rb@Wkr. Out bf16.
__global__ __launch_bounds__(256) void proj_mfma(
    const short* __restrict__ Eb, const short* __restrict__ Evb,
    const short* __restrict__ Rb, const short* __restrict__ Wt,
    short* __restrict__ qb, short* __restrict__ kb,
    short* __restrict__ vb, short* __restrict__ Qpb) {
  const int z = blockIdx.z;
  const short* A; const short* Bt; short* C; int M;
  const size_t MM = (size_t)D_ * D_;
  if (z == 0)      { A = Eb;  Bt = Wt;          C = qb;  M = B_ * L_; }
  else if (z == 1) { A = Evb; Bt = Wt + MM;     C = kb;  M = B_ * L_; }
  else if (z == 2) { A = Evb; Bt = Wt + 3 * MM; C = vb;  M = B_ * L_; }
  else             { A = Rb;  Bt = Wt + 2 * MM; C = Qpb; M = L_;      }
  if ((int)blockIdx.y * 64 >= M) return;
  mm_nf<4, 0>(A, Bt, C, D_, D_, blockIdx.x, blockIdx.y);
}

__global__ __launch_bounds__(256) void out_mfma(
    const short* __restrict__ Ob, const short* __restrict__ Wot, float* __restrict__ proj) {
  mm_nf<2, 1>(Ob, Wot, proj, D_, D_, blockIdx.x, blockIdx.y);
}

// ---------------------------------------------------------------------------
// cvec[b,h,j] = cb_h . k[b,j,h];  dvec[h,m] = pb_h . Qp[m,h]
// ---------------------------------------------------------------------------
__global__ __launch_bounds__(256) void cdvec(
    const short* __restrict__ kb, const short* __restrict__ Qpb,
    const float* __restrict__ cb, const float* __restrict__ pb,
    float* __restrict__ cvec, float* __restrict__ dvec) {
  int idx = blockIdx.x * 256 + threadIdx.x;
  if (idx < B_ * H_ * L_) {
    int b = idx >> 14, h = (idx >> 10) & 15, j = idx & 1023;
    const short* kr = &kb[(size_t)(b * L_ + j) * D_ + h * 64];
    const float* cr = &cb[h * 64];
    float s = 0.f;
    #pragma unroll
    for (int d8 = 0; d8 < 8; ++d8) {
      short8 kv = *(const short8*)&kr[d8 * 8];
      #pragma unroll
      for (int e = 0; e < 8; ++e) s += bf2f(kv[e]) * cr[d8 * 8 + e];
    }
    cvec[idx] = s;
  } else {
    int i2 = idx - B_ * H_ * L_;
    if (i2 < H_ * L_) {
      int h = i2 >> 10, m = i2 & 1023;
      const short* qr = &Qpb[(size_t)m * D_ + h * 64];
      const float* pr = &pb[h * 64];
      float s = 0.f;
      #pragma unroll
      for (int d8 = 0; d8 < 8; ++d8) {
        short8 qv = *(const short8*)&qr[d8 * 8];
        #pragma unroll
        for (int e = 0; e < 8; ++e) s += bf2f(qv[e]) * pr[d8 * 8 + e];
      }
      dvec[i2] = s;
    }
  }
}

// ---------------------------------------------------------------------------
// MFMA attention, flash split-K over j. Block = 64 q-rows of one (b,h),
// split = blockIdx.y handles j-tiles [split*8, split*8+8). Unnormalized
// partials (O', m, l) out; combine kernel merges.
// ---------------------------------------------------------------------------
__global__ __launch_bounds__(256) void attn_mfma(
    const short* __restrict__ qb, const short* __restrict__ kb,
    const short* __restrict__ vb, const short* __restrict__ Qpb,
    const float* __restrict__ cvec, const float* __restrict__ dvec,
    float* __restrict__ O0, float* __restrict__ O1, float* __restrict__ ml) {
  __shared__ short k_s[4096];
  __shared__ short vt_s[4096];
  __shared__ short win_s[8192];
  __shared__ short pbq_s[5248];   // union: q staging (4096) | 4x per-wave Pb[16][82]/P[16][64]
  __shared__ float cvec_s[64];
  __shared__ float dvec_s[128];

  const int tid = threadIdx.x;
  const int l = tid & 63, w = tid >> 6;
  const int nib = L_ / 64;
  const int b  = blockIdx.x / (H_ * nib);
  const int hh = (blockIdx.x / nib) % H_;
  const int i0 = (blockIdx.x % nib) * 64;
  const int split = blockIdx.y;
  const int jt0 = split * 8, jt1 = jt0 + 8;
  const f32x4 fz = {0.f, 0.f, 0.f, 0.f};
  const short8 sz = {0, 0, 0, 0, 0, 0, 0, 0};

  short8 rk[2], rv[2], rw[4];
  float rc = 0.f, rd = 0.f;

  auto stage_load = [&](int jt) {
    const int j0 = jt * 64;
    const bool pos = (j0 <= i0);
    const int mbase = L_ - 64 - i0 + j0;
    #pragma unroll
    for (int c = 0; c < 2; ++c) {
      int ci = tid + c * 256;
      int r = ci >> 3, s = ci & 7;
      rk[c] = *(const short8*)&kb[(size_t)(b * L_ + j0 + r) * D_ + hh * 64 + s * 8];
      rv[c] = *(const short8*)&vb[(size_t)(b * L_ + j0 + r) * D_ + hh * 64 + s * 8];
    }
    if (pos) {
      #pragma unroll
      for (int c = 0; c < 4; ++c) {
        int ci = tid + c * 256;
        int mm = ci >> 3, s = ci & 7;
        int m = mbase + mm;
        rw[c] = (m < L_) ? *(const short8*)&Qpb[(size_t)m * D_ + hh * 64 + s * 8] : sz;
      }
      if (tid < 128) {
        int m = mbase + tid;
        rd = (m < L_) ? dvec[hh * L_ + m] : 0.f;
      }
    }
    if (tid < 64) rc = cvec[(size_t)(b * H_ + hh) * L_ + j0 + tid];
  };

  auto stage_write = [&](int jt) {
    const bool pos = (jt * 64 <= i0);
    #pragma unroll
    for (int c = 0; c < 2; ++c) {
      int ci = tid + c * 256;
      int r = ci >> 3, s = ci & 7;
      *(short8*)&k_s[swz(r, s)] = rk[c];
      #pragma unroll
      for (int e = 0; e < 8; ++e) {
        int d = s * 8 + e;
        vt_s[vswz(d, r)] = rv[c][e];
      }
    }
    if (pos) {
      #pragma unroll
      for (int c = 0; c < 4; ++c) {
        int ci = tid + c * 256;
        int mm = ci >> 3, s = ci & 7;
        *(short8*)&win_s[swz(mm, s)] = rw[c];
      }
      if (tid < 128) dvec_s[tid] = rd;
    }
    if (tid < 64) cvec_s[tid] = rc;
  };

  // prologue: q rows via pbq_s (dead after aq read; barrier below protects)
  short8 rq[2];
  #pragma unroll
  for (int c = 0; c < 2; ++c) {
    int ci = tid + c * 256;
    rq[c] = *(const short8*)&qb[(size_t)(b * L_ + i0 + (ci >> 3)) * D_ + hh * 64 + (ci & 7) * 8];
  }
  stage_load(jt0);
  #pragma unroll
  for (int c = 0; c < 2; ++c) {
    int ci = tid + c * 256;
    *(short8*)&pbq_s[swz(ci >> 3, ci & 7)] = rq[c];
  }
  __syncthreads();

  short8 aq[2];
  {
    int row = w * 16 + (l & 15);
    aq[0] = *(const short8*)&pbq_s[swz(row, (l >> 4))];
    aq[1] = *(const short8*)&pbq_s[swz(row, 4 + (l >> 4))];
  }

  float mrow[4], lrow[4];
  f32x4 oacc[4];
  #pragma unroll
  for (int r = 0; r < 4; ++r) { mrow[r] = -3.0e38f; lrow[r] = 0.f; }
  #pragma unroll
  for (int nf = 0; nf < 4; ++nf) oacc[nf] = fz;

  for (int jt = jt0; jt < jt1; ++jt) {
    const int j0 = jt * 64;
    const bool pos = (j0 <= i0);
    const bool diag = (j0 == i0);

    stage_write(jt);                 // barrier below also protects pbq union
    __syncthreads();
    if (jt + 1 < jt1) stage_load(jt + 1);   // T14: next-tile globals in flight

    // QK^T
    f32x4 sac[4];
    #pragma unroll
    for (int nf = 0; nf < 4; ++nf) sac[nf] = fz;
    __builtin_amdgcn_s_setprio(1);
    #pragma unroll
    for (int kf = 0; kf < 2; ++kf) {
      #pragma unroll
      for (int nf = 0; nf < 4; ++nf) {
        short8 bk = *(const short8*)&k_s[swz(nf * 16 + (l & 15), kf * 4 + (l >> 4))];
        sac[nf] = __builtin_amdgcn_mfma_f32_16x16x32_bf16(aq[kf], bk, sac[nf], 0, 0, 0);
      }
    }
    __builtin_amdgcn_s_setprio(0);

    // positional GEMM over the 80-col per-wave subwindow
    if (pos) {
      f32x4 pacc[5];
      #pragma unroll
      for (int u = 0; u < 5; ++u) pacc[u] = fz;
      const int nf0 = 3 - w;
      __builtin_amdgcn_s_setprio(1);
      #pragma unroll
      for (int kf = 0; kf < 2; ++kf) {
        #pragma unroll
        for (int u = 0; u < 5; ++u) {
          short8 bw = *(const short8*)&win_s[swz((nf0 + u) * 16 + (l & 15), kf * 4 + (l >> 4))];
          pacc[u] = __builtin_amdgcn_mfma_f32_16x16x32_bf16(aq[kf], bw, pacc[u], 0, 0, 0);
        }
      }
      __builtin_amdgcn_s_setprio(0);
      const int pbb = w * 1312;
      #pragma unroll
      for (int u = 0; u < 5; ++u)
        #pragma unroll
        for (int r = 0; r < 4; ++r) {
          int row = (l >> 4) * 4 + r;
          pbq_s[pbb + row * 82 + u * 16 + (l & 15)] = f2bf(pacc[u][r]);
        }
    }

    // biases + shifted positional gather
    #pragma unroll
    for (int nf = 0; nf < 4; ++nf)
      #pragma unroll
      for (int r = 0; r < 4; ++r) {
        int rj = nf * 16 + (l & 15);
        float s = sac[nf][r] + cvec_s[rj];
        if (pos) {
          int ris = (l >> 4) * 4 + r;
          int rib = w * 16 + ris;
          if (!diag || rj <= rib) {
            s += bf2f(pbq_s[w * 1312 + ris * 82 + (15 - ris + rj)]);
            s += dvec_s[63 - rib + rj];
          }
        }
        sac[nf][r] = s;
      }

    // online softmax (16-lane row groups)
    #pragma unroll
    for (int r = 0; r < 4; ++r) {
      float mx = fmaxf(fmaxf(sac[0][r], sac[1][r]), fmaxf(sac[2][r], sac[3][r]));
      #pragma unroll
      for (int off = 1; off < 16; off <<= 1)
        mx = fmaxf(mx, __shfl_xor(mx, off, 64));
      float mn = fmaxf(mrow[r], mx);
      float sc = __expf(mrow[r] - mn);
      mrow[r] = mn;
      float ls = 0.f;
      #pragma unroll
      for (int nf = 0; nf < 4; ++nf) {
        float p = __expf(sac[nf][r] - mn);
        sac[nf][r] = p;
        ls += p;
      }
      #pragma unroll
      for (int off = 1; off < 16; off <<= 1)
        ls += __shfl_xor(ls, off, 64);
      lrow[r] = lrow[r] * sc + ls;
      #pragma unroll
      for (int nf = 0; nf < 4; ++nf) oacc[nf][r] *= sc;
    }

    // P -> bf16, wave-private LDS (pkey swizzle: writes & A-frag reads 2-way)
    #pragma unroll
    for (int nf = 0; nf < 4; ++nf)
      #pragma unroll
      for (int r = 0; r < 4; ++r) {
        int row = (l >> 4) * 4 + r;
        int col = nf * 16 + (l & 15);
        pbq_s[w * 1312 + row * 64 + (((col >> 3) ^ pkey(row)) << 3) + (col & 7)] = f2bf(sac[nf][r]);
      }

    // PV
    __builtin_amdgcn_s_setprio(1);
    #pragma unroll
    for (int kf = 0; kf < 2; ++kf) {
      int prow = l & 15;
      short8 ap = *(const short8*)&pbq_s[w * 1312 + prow * 64 + (((kf * 4 + (l >> 4)) ^ pkey(prow)) << 3)];
      #pragma unroll
      for (int nf = 0; nf < 4; ++nf) {
        short8 bv = *(const short8*)&vt_s[vswz(nf * 16 + (l & 15), (kf * 4 + (l >> 4)) * 8)];
        oacc[nf] = __builtin_amdgcn_mfma_f32_16x16x32_bf16(ap, bv, oacc[nf], 0, 0, 0);
      }
    }
    __builtin_amdgcn_s_setprio(0);
    __syncthreads();
  }

  // unnormalized partial out + (m,l)
  float* Op = split ? O1 : O0;
  #pragma unroll
  for (int r = 0; r < 4; ++r) {
    int ri = (l >> 4) * 4 + r;
    int row = (b * H_ + hh) * L_ + i0 + w * 16 + ri;
    #pragma unroll
    for (int nf = 0; nf < 4; ++nf)
      Op[(size_t)row * 64 + nf * 16 + (l & 15)] = oacc[nf][r];
    if ((l & 15) == 0) {
      ml[split * 65536 + row] = mrow[r];
      ml[split * 65536 + 32768 + row] = lrow[r];
    }
  }
}

// ---------------------------------------------------------------------------
// combine: O = (w0*O0' + w1*O1') / (w0*l0 + w1*l1), w_s = exp(m_s - max m)
// ---------------------------------------------------------------------------
__global__ __launch_bounds__(256) void combine(
    const float* __restrict__ O0, const float* __restrict__ O1,
    const float* __restrict__ ml, short* __restrict__ Ob) {
  int id = blockIdx.x * 256 + threadIdx.x;     // 0..262143
  int row = id >> 3, c8 = (id & 7) * 8;
  float m0 = ml[row],         l0 = ml[32768 + row];
  float m1 = ml[65536 + row], l1 = ml[65536 + 32768 + row];
  float M = fmaxf(m0, m1);
  float w0 = __expf(m0 - M), w1 = __expf(m1 - M);
  float inv = 1.f / (w0 * l0 + w1 * l1);
  const float* p0 = &O0[(size_t)row * 64 + c8];
  const float* p1 = &O1[(size_t)row * 64 + c8];
  short8 o;
  #pragma unroll
  for (int e = 0; e < 8; ++e)
    o[e] = f2bf((w0 * p0[e] + w1 * p1[e]) * inv);
  int b = row >> 14, h = (row >> 10) & 15, i = row & 1023;
  *(short8*)&Ob[(size_t)(b * L_ + i) * D_ + h * 64 + c8] = o;
}

// ---------------------------------------------------------------------------
// res = Ev + proj + Wo_b; LayerNorm * g + b. One block per row.
// ---------------------------------------------------------------------------
__global__ __launch_bounds__(256) void ln_kernel(
    const float* __restrict__ Ev, const float* __restrict__ proj,
    const float* __restrict__ Wo_b, const float* __restrict__ g,
    const float* __restrict__ beta, float* __restrict__ out) {
  const int row = blockIdx.x;
  __shared__ float red[8];
  const int tid = threadIdx.x;
  const int d = tid * 4;

  float4 e  = *(const float4*)&Ev[(size_t)row * D_ + d];
  float4 p  = *(const float4*)&proj[(size_t)row * D_ + d];
  float4 wb = *(const float4*)&Wo_b[d];
  float4 rr = { e.x + p.x + wb.x, e.y + p.y + wb.y,
                e.z + p.z + wb.z, e.w + p.w + wb.w };
  float sum = rr.x + rr.y + rr.z + rr.w;
  float sq  = rr.x * rr.x + rr.y * rr.y + rr.z * rr.z + rr.w * rr.w;

  #pragma unroll
  for (int off = 1; off < 64; off <<= 1) {
    sum += __shfl_xor(sum, off, 64);
    sq  += __shfl_xor(sq,  off, 64);
  }
  const int wid = tid >> 6;
  if ((tid & 63) == 0) { red[wid * 2] = sum; red[wid * 2 + 1] = sq; }
  __syncthreads();
  sum = red[0] + red[2] + red[4] + red[6];
  sq  = red[1] + red[3] + red[5] + red[7];

  const float mu   = sum * (1.f / (float)D_);
  const float var  = sq * (1.f / (float)D_) - mu * mu;
  const float rstd = rsqrtf(var + 1e-5f);

  float4 gg = *(const float4*)&g[d];
  float4 bb = *(const float4*)&beta[d];
  float4 o = { (rr.x - mu) * rstd * gg.x + bb.x,
               (rr.y - mu) * rstd * gg.y + bb.y,
               (rr.z - mu) * rstd * gg.z + bb.z,
               (rr.w - mu) * rstd * gg.w + bb.w };
  *(float4*)&out[(size_t)row * D_ + d] = o;
}

// ---------------------------------------------------------------------------
extern "C" void kernel_launch(void* const* d_in, const int* in_sizes, int n_in,
                              void* d_out, int out_size, void* d_ws, size_t ws_size,
                              hipStream_t stream) {
  const float* E    = (const float*)d_in[0];
  const float* Ev   = (const float*)d_in[1];
  const float* R    = (const float*)d_in[2];
  const float* Wq   = (const float*)d_in[3];
  const float* Wke  = (const float*)d_in[4];
  const float* Wkr  = (const float*)d_in[5];
  const float* Wv   = (const float*)d_in[6];
  const float* cb   = (const float*)d_in[7];
  const float* pb   = (const float*)d_in[8];
  const float* Wo_w = (const float*)d_in[9];
  const float* Wo_b = (const float*)d_in[10];
  const float* ln_g = (const float*)d_in[11];
  const float* ln_b = (const float*)d_in[12];
  float* out = (float*)d_out;

  // ws (shorts): Eb 2M | Evb 2M | Rb 1M | qb 2M | kb 2M | vb 2M | Qpb 1M |
  // Wt 5M | Ob 2M = 19M shorts = 38MB.
  // Sequential-reuse aliases: O0 partial (8MB f32) over Eb+Evb (dead after
  // proj); O1 (8MB f32) over Wt[0..4M) (proj weights dead after proj); ml in
  // Rb tail after cvec/dvec; proj fp32 over Eb+Evb (after combine).
  short* ws   = (short*)d_ws;
  short* Eb   = ws;
  short* Evb  = ws + 2097152;
  short* Rb   = ws + 4194304;
  short* qb   = ws + 5242880;
  short* kb   = ws + 7340032;
  short* vb   = ws + 9437184;
  short* Qpb  = ws + 11534336;
  short* Wt   = ws + 12582912;
  short* Ob   = ws + 17825792;
  float* proj = (float*)Eb;
  float* cvec = (float*)Rb;
  float* dvec = cvec + 32768;
  float* ml   = dvec + 16384;        // 4*32768 floats, fits in Rb (2MB)
  float* O0   = (float*)Eb;          // attn partials (before proj write)
  float* O1   = (float*)Wt;

  // 1) prep: cast activations + transpose/cast weights
  prep<<<3840, 256, 0, stream>>>(E, Ev, R, Wq, Wke, Wkr, Wv, Wo_w, Eb, Wt);

  // 2) projections -> bf16 q,k,v,Qp  (64x128 tiles, 1024 blocks)
  proj_mfma<<<dim3(8, 32, 4), 256, 0, stream>>>(Eb, Evb, Rb, Wt, qb, kb, vb, Qpb);

  // 3) bias scalars
  cdvec<<<192, 256, 0, stream>>>(kb, Qpb, cb, pb, cvec, dvec);

  // 4) attention partials (split-K over j, 1024 blocks)
  attn_mfma<<<dim3(B_ * H_ * (L_ / 64), 2), 256, 0, stream>>>(
      qb, kb, vb, Qpb, cvec, dvec, O0, O1, ml);

  // 5) combine partials -> bf16 O
  combine<<<1024, 256, 0, stream>>>(O0, O1, ml, Ob);

  // 6) output projection -> fp32 proj (64x64 tiles, 512 blocks)
  out_mfma<<<dim3(16, 32), 256, 0, stream>>>(Ob, Wt + 4 * (size_t)D_ * D_, proj);

  // 7) residual + LayerNorm
  ln_kernel<<<B_ * L_, 256, 0, stream>>>(Ev, proj, Wo_b, ln_g, ln_b, out);
}